// Round 7
// baseline (5243.641 us; speedup 1.0000x reference)
//
#include <hip/hip_runtime.h>
#include <hip/hip_bf16.h>

#define DEV __device__ __forceinline__

constexpr int B_ = 256;   // batch
constexpr int T_ = 512;   // time
constexpr int H_ = 128;   // GRU units
constexpr int K_ = 256;   // input dim per layer (D = 2H = 256 for all layers)
constexpr int G_ = 384;   // 3H
constexpr int M_ = B_ * T_;
constexpr int LDSROW = 72;  // ushorts per LDS tile row (64 data + 8 pad)

using bf16 = __hip_bfloat16;
typedef short bf16x8 __attribute__((ext_vector_type(8)));
typedef float f32x4 __attribute__((ext_vector_type(4)));
typedef float f32x2 __attribute__((ext_vector_type(2)));

DEV float tof(float x) { return x; }
DEV float tof(bf16 x) { return __bfloat162float(x); }
DEV void stor(float* p, float v) { *p = v; }
DEV void stor(bf16* p, float v) { *p = __float2bfloat16(v); }

// float -> bf16 bits, round-to-nearest-even
DEV unsigned short f2bs(float f) {
  union { float f; unsigned u; } v;
  v.f = f;
  unsigned r = (v.u + 0x7FFFu + ((v.u >> 16) & 1u)) >> 16;
  return (unsigned short)r;
}
DEV float bs2f(unsigned short s) {
  union { unsigned u; float f; } v;
  v.u = ((unsigned)s) << 16;
  return v.f;
}

DEV float fsigmoid(float x) { return 1.f / (1.f + __expf(-x)); }
DEV float ftanh(float x) {
  x = fminf(20.f, fmaxf(-20.f, x));
  float e = __expf(-2.f * x);
  return (1.f - e) / (1.f + e);
}

// Barrier draining only LDS traffic (lgkmcnt), not global loads/stores.
DEV void barrier_lds() {
  asm volatile("s_waitcnt lgkmcnt(0)\n\ts_barrier" ::: "memory");
}

// Pin a float4 into VGPRs (opaque to the optimizer). v0 precedent: 16 pinned
// float4s (64 regs) stay resident (VGPR_Count 68, 590us); 32 spill (v2).
DEV void pin4(float4& v) {
  asm volatile("" : "+v"(v.x), "+v"(v.y), "+v"(v.z), "+v"(v.w));
}

// 4-lane butterfly sum on the VALU pipe (DPP quad_perm), masks xor1/xor2.
DEV float dpp_red4(float x) {
  int t;
  t = __builtin_amdgcn_update_dpp(0, __float_as_int(x), 0xB1, 0xF, 0xF, true);
  x += __int_as_float(t);
  t = __builtin_amdgcn_update_dpp(0, __float_as_int(x), 0x4E, 0xF, 0xF, true);
  x += __int_as_float(t);
  return x;
}

DEV f32x4 mfma16(bf16x8 a, bf16x8 b, f32x4 c) {
  return __builtin_amdgcn_mfma_f32_16x16x32_bf16(a, b, c, 0, 0, 0);
}

// ---------------------------------------------------------------------------
// convX: split fp32 x[M,256] into bf16 hi/lo arrays (layer-0 GEMM input).
// ---------------------------------------------------------------------------
__global__ __launch_bounds__(256) void convX_kernel(
    const float* __restrict__ x, ushort* __restrict__ hiA,
    ushort* __restrict__ loA) {
  const int n4 = M_ * K_ / 4;
  for (int idx = blockIdx.x * blockDim.x + threadIdx.x; idx < n4;
       idx += gridDim.x * blockDim.x) {
    float4 v = ((const float4*)x)[idx];
    ushort4 h, l;
    h.x = f2bs(v.x); l.x = f2bs(v.x - bs2f(h.x));
    h.y = f2bs(v.y); l.y = f2bs(v.y - bs2f(h.y));
    h.z = f2bs(v.z); l.z = f2bs(v.z - bs2f(h.z));
    h.w = f2bs(v.w); l.w = f2bs(v.w - bs2f(h.w));
    ((ushort4*)hiA)[idx] = h;
    ((ushort4*)loA)[idx] = l;
  }
}

// ---------------------------------------------------------------------------
// convW: W[dir][256][384] fp32 -> W^T hi/lo bf16 [768 ncol][256 k].
// ---------------------------------------------------------------------------
__global__ __launch_bounds__(256) void convW_kernel(
    const float* __restrict__ W, ushort* __restrict__ WhiT,
    ushort* __restrict__ WloT) {
  const int ncol = blockIdx.x;           // 0..767
  const int dir = ncol / G_, j = ncol % G_;
  const int k = threadIdx.x;             // 0..255
  const float f = W[((size_t)dir * K_ + k) * G_ + j];
  const unsigned short hi = f2bs(f);
  WhiT[(size_t)ncol * K_ + k] = hi;
  WloT[(size_t)ncol * K_ + k] = f2bs(f - bs2f(hi));
}

// ---------------------------------------------------------------------------
// gemm3: C[M,768] = A[M,256] @ W^T' + bias, bf16 hi/lo 3-term split MFMA.
// Epilogue reverted to the round-0 xp layout [dir][t][b][g] (the v4 rec-
// friendly scatter layout stored 4B at stride 64B and regressed gemm3).
// ---------------------------------------------------------------------------
template <typename XT>
__global__ __launch_bounds__(256, 2) void gemm3_kernel(
    const ushort* __restrict__ Ahi, const ushort* __restrict__ Alo,
    const ushort* __restrict__ WhiT, const ushort* __restrict__ WloT,
    const float* __restrict__ bbias, XT* __restrict__ xp) {
  const int m0 = blockIdx.x * 128;
  const int n0 = blockIdx.y * 128;
  const int tid = threadIdx.x;
  const int w = tid >> 6, lane = tid & 63;
  const int wm = w >> 1, wn = w & 1;
  const int col = lane & 15, quad = lane >> 4;

  __shared__ __align__(16) ushort AH[128 * LDSROW];
  __shared__ __align__(16) ushort AL[128 * LDSROW];
  __shared__ __align__(16) ushort BH[128 * LDSROW];
  __shared__ __align__(16) ushort BL[128 * LDSROW];

  f32x4 acc[4][4];
#pragma unroll
  for (int i = 0; i < 4; ++i)
#pragma unroll
    for (int n = 0; n < 4; ++n) acc[i][n] = (f32x4){0.f, 0.f, 0.f, 0.f};

  const ushort* gsrc = (w == 0) ? Ahi : (w == 1) ? Alo : (w == 2) ? WhiT : WloT;
  ushort* lds = (w == 0) ? AH : (w == 1) ? AL : (w == 2) ? BH : BL;
  const int rbase = (w < 2) ? m0 : n0;

  for (int kb = 0; kb < K_; kb += 64) {
#pragma unroll
    for (int q = 0; q < 16; ++q) {
      const int slot = q * 64 + lane;
      const int r = slot >> 3, s = slot & 7;
      bf16x8 v = *(const bf16x8*)(gsrc + (size_t)(rbase + r) * K_ + kb + s * 8);
      *(bf16x8*)&lds[r * LDSROW + s * 8] = v;
    }
    __syncthreads();
#pragma unroll
    for (int z = 0; z < 2; ++z) {
      const int cc8 = (z * 4 + quad) * 8;
      bf16x8 ah[4], al[4], bh[4], bl[4];
#pragma unroll
      for (int i = 0; i < 4; ++i) {
        const int row = wm * 64 + i * 16 + col;
        ah[i] = *(const bf16x8*)&AH[row * LDSROW + cc8];
        al[i] = *(const bf16x8*)&AL[row * LDSROW + cc8];
      }
#pragma unroll
      for (int n = 0; n < 4; ++n) {
        const int row = wn * 64 + n * 16 + col;
        bh[n] = *(const bf16x8*)&BH[row * LDSROW + cc8];
        bl[n] = *(const bf16x8*)&BL[row * LDSROW + cc8];
      }
#pragma unroll
      for (int i = 0; i < 4; ++i)
#pragma unroll
        for (int n = 0; n < 4; ++n) {
          acc[i][n] = mfma16(ah[i], bh[n], acc[i][n]);
          acc[i][n] = mfma16(al[i], bh[n], acc[i][n]);
          acc[i][n] = mfma16(ah[i], bl[n], acc[i][n]);
        }
    }
    __syncthreads();
  }

  const int dir = (n0 >= G_) ? 1 : 0;
#pragma unroll
  for (int n = 0; n < 4; ++n) {
    const int ncol = n0 + wn * 64 + n * 16 + col;
    const int g = ncol - dir * G_;
    const float bv = bbias[dir * 2 * G_ + g];
#pragma unroll
    for (int i = 0; i < 4; ++i) {
      const int mb = m0 + wm * 64 + i * 16 + quad * 4;
#pragma unroll
      for (int r = 0; r < 4; ++r) {
        const int m = mb + r;
        const int bb = m >> 9;          // T_ = 512
        const int t = m & (T_ - 1);
        stor(xp + ((size_t)(dir * T_ + t) * B_ + bb) * G_ + g,
             acc[i][n][r] + bv);
      }
    }
  }
}

DEV float4 ldU4(const float* U, int col, int k0) {
  float4 v;
  v.x = U[(size_t)(k0 + 0) * G_ + col];
  v.y = U[(size_t)(k0 + 1) * G_ + col];
  v.z = U[(size_t)(k0 + 2) * G_ + col];
  v.w = U[(size_t)(k0 + 3) * G_ + col];
  return v;
}

// ---------------------------------------------------------------------------
// Recurrence, v6 (VALU, back to the v0 envelope). Grid (256, 2): ONE seq per
// block, 768 threads, 512 blocks -> TWO blocks per CU.
//
// v3-v5 post-mortem: MFMA rec needs 48KB/wave of U fragments vs 32KB arch
// VGPR -> structural spill, 3900cy/step, insensitive to pin/AGPR tricks.
// v0 (590us) proved 64 U-regs/thread stays resident. v6 keeps that envelope
// and fixes v0's two measured overheads:
//  (1) reduction span 8->4 lanes: thread = (2 cols, k-quarter), 16 reduce
//      ops instead of 48, same 8 ds_read_b128, same 32 pk_fma.
//  (2) 1 seq/block -> 2 blocks/CU: one block's gate bubble + barrier waits
//      are covered by the co-resident block's dot phase.
// k-subsets interleaved (kq*4 + 16j) so the 4 kq read-addresses per wave hit
// disjoint bank-quads -> conflict-free broadcast reads.
// ---------------------------------------------------------------------------
template <typename XT, bool LAST>
__global__ __attribute__((amdgpu_flat_work_group_size(768, 768),
                          amdgpu_waves_per_eu(6))) void rec_kernel(
    const XT* __restrict__ xp, const float* __restrict__ Ubase,
    const float* __restrict__ bbase, ushort* __restrict__ seqH,
    ushort* __restrict__ seqL, float* __restrict__ fin) {
  const int dir = blockIdx.y;
  const int b = blockIdx.x;
  const float* U = Ubase + dir * (H_ * G_);
  const float* bh = bbase + dir * (2 * G_) + G_;
  const int tid = threadIdx.x;
  const int kq = tid & 3;        // k-quarter selector (lane bits 0-1)
  const int cg = tid >> 2;       // column group 0..191
  const int c0 = cg * 2, c1 = c0 + 1;
  const bool gateT = tid < H_;

  __shared__ __align__(16) float hbuf[2][H_];
  __shared__ float rec_s[G_];

  // U fragments: u0/u1[j] covers cols c0/c1, k in {kq*4 + 16j .. +4}
  float4 u0[8], u1[8];
#pragma unroll
  for (int j = 0; j < 8; ++j) {
    u0[j] = ldU4(U, c0, kq * 4 + 16 * j);
    u1[j] = ldU4(U, c1, kq * 4 + 16 * j);
    pin4(u0[j]);
    pin4(u1[j]);
  }

  const int wcol = c0 + (kq & 1);     // kq0 writes c0, kq1 writes c1
  const float bmine = bh[wcol];

  if (gateT) {
    hbuf[0][tid] = 0.f;
    hbuf[1][tid] = 0.f;
  }

  const XT* xbase = xp + (size_t)(dir * T_) * B_ * G_;

  XT xzc{}, xrc{}, xhc{};
  if (gateT) {
    const int t0 = dir ? (T_ - 1) : 0;
    const XT* xr_ = xbase + ((size_t)t0 * B_ + b) * G_ + tid;
    xzc = xr_[0];
    xrc = xr_[H_];
    xhc = xr_[2 * H_];
  }
  float hprev = 0.f;   // gate thread's own h, carried in-register
  barrier_lds();

  for (int it = 0; it < T_; ++it) {
    const int t = dir ? (T_ - 1 - it) : it;
    const int cur = it & 1, nxt = cur ^ 1;

    // --- prefetch xp for step it+1 (hidden under the dot phase) ---
    XT xzn = xzc, xrn = xrc, xhn = xhc;
    if (gateT && (it + 1 < T_)) {
      const int tn = dir ? (t - 1) : (t + 1);
      const XT* xr_ = xbase + ((size_t)tn * B_ + b) * G_ + tid;
      xzn = xr_[0];
      xrn = xr_[H_];
      xhn = xr_[2 * H_];
    }

    // --- dot phase: 2 cols x 32 k, 8 broadcast ds_read_b128, 32 pk_fma ---
    f32x2 a00 = {0.f, 0.f}, a01 = {0.f, 0.f};
    f32x2 a10 = {0.f, 0.f}, a11 = {0.f, 0.f};
#pragma unroll
    for (int j = 0; j < 8; j += 2) {
      const float4 h0 = *(const float4*)&hbuf[cur][kq * 4 + 16 * j];
      const float4 h1 = *(const float4*)&hbuf[cur][kq * 4 + 16 * (j + 1)];
      const f32x2* hp0 = (const f32x2*)&h0;
      const f32x2* hp1 = (const f32x2*)&h1;
      const f32x2* p00 = (const f32x2*)&u0[j];
      const f32x2* p10 = (const f32x2*)&u1[j];
      const f32x2* p01 = (const f32x2*)&u0[j + 1];
      const f32x2* p11 = (const f32x2*)&u1[j + 1];
      a00 = __builtin_elementwise_fma(hp0[0], p00[0], a00);
      a00 = __builtin_elementwise_fma(hp0[1], p00[1], a00);
      a10 = __builtin_elementwise_fma(hp0[0], p10[0], a10);
      a10 = __builtin_elementwise_fma(hp0[1], p10[1], a10);
      a01 = __builtin_elementwise_fma(hp1[0], p01[0], a01);
      a01 = __builtin_elementwise_fma(hp1[1], p01[1], a01);
      a11 = __builtin_elementwise_fma(hp1[0], p11[0], a11);
      a11 = __builtin_elementwise_fma(hp1[1], p11[1], a11);
    }
    a00 += a01;
    a10 += a11;
    float s0 = a00.x + a00.y;
    float s1 = a10.x + a10.y;
    s0 = dpp_red4(s0);
    s1 = dpp_red4(s1);
    if (kq < 2) rec_s[wcol] = (kq == 0 ? s0 : s1) + bmine;
    barrier_lds();

    // --- gate phase (first 128 threads; co-resident block overlaps) ---
    if (gateT) {
      const float xz = tof(xzc);
      const float xr = tof(xrc);
      const float xh = tof(xhc);
      const float rz = rec_s[tid];
      const float rr = rec_s[H_ + tid];
      const float rh = rec_s[2 * H_ + tid];
      const float z = fsigmoid(xz + rz);
      const float r = fsigmoid(xr + rr);
      const float hh = ftanh(xh + r * rh);
      const float hn = z * hprev + (1.f - z) * hh;
      hprev = hn;
      hbuf[nxt][tid] = hn;
      if constexpr (!LAST) {
        const size_t sidx = ((size_t)b * T_ + t) * (2 * H_) + dir * H_ + tid;
        const unsigned short hi = f2bs(hn);
        seqH[sidx] = hi;
        seqL[sidx] = f2bs(hn - bs2f(hi));
      }
      xzc = xzn;
      xrc = xrn;
      xhc = xhn;
    }
    barrier_lds();
  }

  if constexpr (LAST) {
    if (gateT) fin[(size_t)b * (2 * H_) + dir * H_ + tid] = hprev;
  }
}

// ---------------------------------------------------------------------------
// Dense head: out[b] = sigmoid(fin[b][:] . Wd + bd)
// ---------------------------------------------------------------------------
__global__ void dense_kernel(const float* __restrict__ fin,
                             const float* __restrict__ Wd,
                             const float* __restrict__ bd,
                             float* __restrict__ out) {
  __shared__ float w[2 * H_];
  const int tid = threadIdx.x;
  w[tid] = Wd[tid];
  __syncthreads();
  float s = bd[0];
  const float* row = fin + tid * (2 * H_);
#pragma unroll 8
  for (int jj = 0; jj < 2 * H_; ++jj) s = fmaf(row[jj], w[jj], s);
  out[tid] = 1.f / (1.f + __expf(-s));
}

// ---------------------------------------------------------------------------
template <typename XT>
static void run_model(const float* x, const float* Ws, const float* Us,
                      const float* bs, const float* Wd, const float* bd,
                      float* out, char* ws, hipStream_t stream) {
  const size_t xpB = (size_t)2 * T_ * B_ * G_ * sizeof(XT);
  const size_t seqB = (size_t)B_ * T_ * 2 * H_ * 2;  // bf16 bits
  XT* xp = (XT*)ws;
  ushort* sHA = (ushort*)(ws + xpB);
  ushort* sLA = (ushort*)(ws + xpB + seqB);
  ushort* sHB = (ushort*)(ws + xpB + 2 * seqB);
  ushort* sLB = (ushort*)(ws + xpB + 3 * seqB);
  ushort* WhiT = (ushort*)(ws + xpB + 4 * seqB);
  ushort* WloT = WhiT + (size_t)768 * K_;
  float* fin = (float*)(ws + xpB + 4 * seqB + (size_t)2 * 768 * K_ * 2);

  convX_kernel<<<4096, 256, 0, stream>>>(x, sHB, sLB);

  const ushort* AHs[3] = {sHB, sHA, sHB};
  const ushort* ALs[3] = {sLB, sLA, sLB};
  ushort* oH[3] = {sHA, sHB, nullptr};
  ushort* oL[3] = {sLA, sLB, nullptr};

  for (int l = 0; l < 3; ++l) {
    const float* Wl = Ws + (size_t)l * 2 * K_ * G_;
    const float* bl = bs + (size_t)l * 4 * G_;
    const float* Ul = Us + (size_t)l * 2 * H_ * G_;
    convW_kernel<<<768, 256, 0, stream>>>(Wl, WhiT, WloT);
    gemm3_kernel<XT><<<dim3(M_ / 128, 6), 256, 0, stream>>>(
        AHs[l], ALs[l], WhiT, WloT, bl, xp);
    if (l < 2)
      rec_kernel<XT, false><<<dim3(B_, 2), 768, 0, stream>>>(
          xp, Ul, bl, oH[l], oL[l], nullptr);
    else
      rec_kernel<XT, true><<<dim3(B_, 2), 768, 0, stream>>>(
          xp, Ul, bl, nullptr, nullptr, fin);
  }
  dense_kernel<<<1, B_, 0, stream>>>(fin, Wd, bd, out);
}

extern "C" void kernel_launch(void* const* d_in, const int* in_sizes, int n_in,
                              void* d_out, int out_size, void* d_ws,
                              size_t ws_size, hipStream_t stream) {
  const float* x = (const float*)d_in[0];
  const float* Ws = (const float*)d_in[1];
  const float* Us = (const float*)d_in[2];
  const float* bs = (const float*)d_in[3];
  const float* Wd = (const float*)d_in[4];
  const float* bd = (const float*)d_in[5];
  float* out = (float*)d_out;
  char* ws = (char*)d_ws;

  const size_t seqB = (size_t)B_ * T_ * 2 * H_ * 2;
  const size_t wtB = (size_t)2 * 768 * K_ * 2;
  const size_t finB = (size_t)B_ * 2 * H_ * 4;
  const size_t xp32 = (size_t)2 * T_ * B_ * G_ * 4;
  const size_t tierA = xp32 + 4 * seqB + wtB + finB;      // ~641 MiB, fp32 xp
  if (ws_size >= tierA)
    run_model<float>(x, Ws, Us, bs, Wd, bd, out, ws, stream);
  else
    run_model<bf16>(x, Ws, Us, bs, Wd, bd, out, ws, stream);
}

// Round 9
// 2277.202 us; speedup vs baseline: 2.3027x; 2.3027x over previous
//
#include <hip/hip_runtime.h>
#include <hip/hip_bf16.h>

#define DEV __device__ __forceinline__

constexpr int B_ = 256;   // batch
constexpr int T_ = 512;   // time
constexpr int H_ = 128;   // GRU units
constexpr int K_ = 256;   // input dim per layer (D = 2H = 256 for all layers)
constexpr int G_ = 384;   // 3H
constexpr int M_ = B_ * T_;
constexpr int LDSROW = 72;  // ushorts per LDS tile row (64 data + 8 pad)

using bf16 = __hip_bfloat16;
typedef short bf16x8 __attribute__((ext_vector_type(8)));
typedef float f32x4 __attribute__((ext_vector_type(4)));
typedef float f32x2 __attribute__((ext_vector_type(2)));

DEV float tof(float x) { return x; }
DEV float tof(bf16 x) { return __bfloat162float(x); }
DEV void stor(float* p, float v) { *p = v; }
DEV void stor(bf16* p, float v) { *p = __float2bfloat16(v); }

// float -> bf16 bits, round-to-nearest-even
DEV unsigned short f2bs(float f) {
  union { float f; unsigned u; } v;
  v.f = f;
  unsigned r = (v.u + 0x7FFFu + ((v.u >> 16) & 1u)) >> 16;
  return (unsigned short)r;
}
DEV float bs2f(unsigned short s) {
  union { unsigned u; float f; } v;
  v.u = ((unsigned)s) << 16;
  return v.f;
}

// v7: fast-rcp gate math. IEEE fp32 div expands to ~10-15 v_div_* ops; the
// gate phase sits between both barriers so all 12 waves pay for it.
// __builtin_amdgcn_rcpf is 1 op, ~1 ulp — harmless downstream of exp.
DEV float fsigmoid(float x) {
  return __builtin_amdgcn_rcpf(1.f + __expf(-x));
}
DEV float ftanh(float x) {
  x = fminf(20.f, fmaxf(-20.f, x));
  float e = __expf(-2.f * x);
  return (1.f - e) * __builtin_amdgcn_rcpf(1.f + e);
}

// Barrier draining only LDS traffic (lgkmcnt), not global loads/stores.
DEV void barrier_lds() {
  asm volatile("s_waitcnt lgkmcnt(0)\n\ts_barrier" ::: "memory");
}

// Pin a float4 into VGPRs (opaque to the optimizer).
DEV void pin4(float4& v) {
  asm volatile("" : "+v"(v.x), "+v"(v.y), "+v"(v.z), "+v"(v.w));
}

DEV f32x4 mfma16(bf16x8 a, bf16x8 b, f32x4 c) {
  return __builtin_amdgcn_mfma_f32_16x16x32_bf16(a, b, c, 0, 0, 0);
}

// Butterfly sum over 8-lane groups, entirely on the VALU pipe (DPP), keeping
// the LDS pipe free. Masks {1,2,7}: quad_perm[1,0,3,2]=0xB1, quad_perm[2,3,0,1]
// =0x4E, row_half_mirror=0x141 (xor7 group-local). Span{1,2,7} = full 8-group.
DEV float dpp_red8(float x) {
  int t;
  t = __builtin_amdgcn_update_dpp(0, __float_as_int(x), 0xB1, 0xF, 0xF, true);
  x += __int_as_float(t);
  t = __builtin_amdgcn_update_dpp(0, __float_as_int(x), 0x4E, 0xF, 0xF, true);
  x += __int_as_float(t);
  t = __builtin_amdgcn_update_dpp(0, __float_as_int(x), 0x141, 0xF, 0xF, true);
  x += __int_as_float(t);
  return x;
}

// ---------------------------------------------------------------------------
// convX: split fp32 x[M,256] into bf16 hi/lo arrays (layer-0 GEMM input).
// ---------------------------------------------------------------------------
__global__ __launch_bounds__(256) void convX_kernel(
    const float* __restrict__ x, ushort* __restrict__ hiA,
    ushort* __restrict__ loA) {
  const int n4 = M_ * K_ / 4;
  for (int idx = blockIdx.x * blockDim.x + threadIdx.x; idx < n4;
       idx += gridDim.x * blockDim.x) {
    float4 v = ((const float4*)x)[idx];
    ushort4 h, l;
    h.x = f2bs(v.x); l.x = f2bs(v.x - bs2f(h.x));
    h.y = f2bs(v.y); l.y = f2bs(v.y - bs2f(h.y));
    h.z = f2bs(v.z); l.z = f2bs(v.z - bs2f(h.z));
    h.w = f2bs(v.w); l.w = f2bs(v.w - bs2f(h.w));
    ((ushort4*)hiA)[idx] = h;
    ((ushort4*)loA)[idx] = l;
  }
}

// ---------------------------------------------------------------------------
// convW: W[dir][256][384] fp32 -> W^T hi/lo bf16 [768 ncol][256 k].
// ---------------------------------------------------------------------------
__global__ __launch_bounds__(256) void convW_kernel(
    const float* __restrict__ W, ushort* __restrict__ WhiT,
    ushort* __restrict__ WloT) {
  const int ncol = blockIdx.x;           // 0..767
  const int dir = ncol / G_, j = ncol % G_;
  const int k = threadIdx.x;             // 0..255
  const float f = W[((size_t)dir * K_ + k) * G_ + j];
  const unsigned short hi = f2bs(f);
  WhiT[(size_t)ncol * K_ + k] = hi;
  WloT[(size_t)ncol * K_ + k] = f2bs(f - bs2f(hi));
}

// ---------------------------------------------------------------------------
// gemm3: C[M,768] = A[M,256] @ W^T' + bias, bf16 hi/lo 3-term split MFMA.
// ---------------------------------------------------------------------------
template <typename XT>
__global__ __launch_bounds__(256, 2) void gemm3_kernel(
    const ushort* __restrict__ Ahi, const ushort* __restrict__ Alo,
    const ushort* __restrict__ WhiT, const ushort* __restrict__ WloT,
    const float* __restrict__ bbias, XT* __restrict__ xp) {
  const int m0 = blockIdx.x * 128;
  const int n0 = blockIdx.y * 128;
  const int tid = threadIdx.x;
  const int w = tid >> 6, lane = tid & 63;
  const int wm = w >> 1, wn = w & 1;
  const int col = lane & 15, quad = lane >> 4;

  __shared__ __align__(16) ushort AH[128 * LDSROW];
  __shared__ __align__(16) ushort AL[128 * LDSROW];
  __shared__ __align__(16) ushort BH[128 * LDSROW];
  __shared__ __align__(16) ushort BL[128 * LDSROW];

  f32x4 acc[4][4];
#pragma unroll
  for (int i = 0; i < 4; ++i)
#pragma unroll
    for (int n = 0; n < 4; ++n) acc[i][n] = (f32x4){0.f, 0.f, 0.f, 0.f};

  const ushort* gsrc = (w == 0) ? Ahi : (w == 1) ? Alo : (w == 2) ? WhiT : WloT;
  ushort* lds = (w == 0) ? AH : (w == 1) ? AL : (w == 2) ? BH : BL;
  const int rbase = (w < 2) ? m0 : n0;

  for (int kb = 0; kb < K_; kb += 64) {
#pragma unroll
    for (int q = 0; q < 16; ++q) {
      const int slot = q * 64 + lane;
      const int r = slot >> 3, s = slot & 7;
      bf16x8 v = *(const bf16x8*)(gsrc + (size_t)(rbase + r) * K_ + kb + s * 8);
      *(bf16x8*)&lds[r * LDSROW + s * 8] = v;
    }
    __syncthreads();
#pragma unroll
    for (int z = 0; z < 2; ++z) {
      const int cc8 = (z * 4 + quad) * 8;
      bf16x8 ah[4], al[4], bh[4], bl[4];
#pragma unroll
      for (int i = 0; i < 4; ++i) {
        const int row = wm * 64 + i * 16 + col;
        ah[i] = *(const bf16x8*)&AH[row * LDSROW + cc8];
        al[i] = *(const bf16x8*)&AL[row * LDSROW + cc8];
      }
#pragma unroll
      for (int n = 0; n < 4; ++n) {
        const int row = wn * 64 + n * 16 + col;
        bh[n] = *(const bf16x8*)&BH[row * LDSROW + cc8];
        bl[n] = *(const bf16x8*)&BL[row * LDSROW + cc8];
      }
#pragma unroll
      for (int i = 0; i < 4; ++i)
#pragma unroll
        for (int n = 0; n < 4; ++n) {
          acc[i][n] = mfma16(ah[i], bh[n], acc[i][n]);
          acc[i][n] = mfma16(al[i], bh[n], acc[i][n]);
          acc[i][n] = mfma16(ah[i], bl[n], acc[i][n]);
        }
    }
    __syncthreads();
  }

  const int dir = (n0 >= G_) ? 1 : 0;
#pragma unroll
  for (int n = 0; n < 4; ++n) {
    const int ncol = n0 + wn * 64 + n * 16 + col;
    const int g = ncol - dir * G_;
    const float bv = bbias[dir * 2 * G_ + g];
#pragma unroll
    for (int i = 0; i < 4; ++i) {
      const int mb = m0 + wm * 64 + i * 16 + quad * 4;
#pragma unroll
      for (int r = 0; r < 4; ++r) {
        const int m = mb + r;
        const int bb = m >> 9;          // T_ = 512
        const int t = m & (T_ - 1);
        stor(xp + ((size_t)(dir * T_ + t) * B_ + bb) * G_ + g,
             acc[i][n][r] + bv);
      }
    }
  }
}

DEV float4 ldU4(const float* U, int col, int k0) {
  float4 v;
  v.x = U[(size_t)(k0 + 0) * G_ + col];
  v.y = U[(size_t)(k0 + 1) * G_ + col];
  v.z = U[(size_t)(k0 + 2) * G_ + col];
  v.w = U[(size_t)(k0 + 3) * G_ + col];
  return v;
}

// ---------------------------------------------------------------------------
// Recurrence, v7 = round-0 v0 RESTORED VERBATIM (measured 590us/launch,
// VGPR 68, the session's best), plus the rcpf gate math above.
//
// Post-mortem summary of why every deviation lost:
//  - v2 (full-k/thread): 128 U regs -> RA wall (~85-100 live max) -> spill.
//  - v3-v5 (MFMA rec): 48KB U fragments/wave vs 32KB arch VGPR -> spill,
//    insensitive to waves_per_eu / AGPR pinning.
//  - v6 (2 blocks/CU): waves_per_eu(6) caps regs at 85 < 64 U + ~25 live ->
//    spill; and 2 co-resident span-4 blocks would need ~192KB/step of LDS
//    reads > 85 B/cy return path anyway.
// Span-8 + 1 block/CU is jointly near-optimal for {VALU issue, LDS return
// BW, register file}: span-4 halves reduce ops but doubles LDS bytes
// (1150->2300 cy/step > VALU time); span-16 halves LDS but doubles reduce.
// ---------------------------------------------------------------------------
template <typename XT, bool LAST>
__global__ __attribute__((amdgpu_flat_work_group_size(768, 768),
                          amdgpu_waves_per_eu(3, 3))) void rec_kernel(
    const XT* __restrict__ xp, const float* __restrict__ Ubase,
    const float* __restrict__ bbase, ushort* __restrict__ seqH,
    ushort* __restrict__ seqL, float* __restrict__ fin) {
  const int dir = blockIdx.y;
  const float* U = Ubase + dir * (H_ * G_);
  const float* bh = bbase + dir * (2 * G_) + G_;
  const int b0 = blockIdx.x * 2;
  const int tid = threadIdx.x;
  const int kc = tid & 7;        // k-chunk selector (lane bits 0-2)
  const int cg = tid >> 3;       // column group 0..95
  const int kc4 = kc * 4;

  __shared__ __align__(16) float hbuf[2][H_];
  __shared__ float rec_s[2][G_];

  // U fragments: u{c}{i} covers col cg*4+c, k in [i*32+kc*4, +4)
#define LDU(c, i) ldU4(U, cg * 4 + (c), (i) * 32 + kc4)
  float4 u00 = LDU(0, 0), u01 = LDU(0, 1), u02 = LDU(0, 2), u03 = LDU(0, 3);
  float4 u10 = LDU(1, 0), u11 = LDU(1, 1), u12 = LDU(1, 2), u13 = LDU(1, 3);
  float4 u20 = LDU(2, 0), u21 = LDU(2, 1), u22 = LDU(2, 2), u23 = LDU(2, 3);
  float4 u30 = LDU(3, 0), u31 = LDU(3, 1), u32 = LDU(3, 2), u33 = LDU(3, 3);
#undef LDU
  pin4(u00); pin4(u01); pin4(u02); pin4(u03);
  pin4(u10); pin4(u11); pin4(u12); pin4(u13);
  pin4(u20); pin4(u21); pin4(u22); pin4(u23);
  pin4(u30); pin4(u31); pin4(u32); pin4(u33);

  const int wc = kc & 3, wr = kc >> 2;     // this thread's rec_s write slot
  const float bmine = bh[cg * 4 + wc];

  const int grow = tid >> 7;        // gate-phase row (tid < 256)
  const int gu = tid & (H_ - 1);    // gate-phase unit
  const bool gateT = tid < 2 * H_;

  if (gateT) hbuf[grow][gu] = 0.f;

  const XT* xbase = xp + (size_t)(dir * T_) * B_ * G_;

  XT xzc{}, xrc{}, xhc{};
  {
    const int t0 = dir ? (T_ - 1) : 0;
    if (gateT) {
      const XT* xr_ = xbase + ((size_t)t0 * B_ + b0 + grow) * G_ + gu;
      xzc = xr_[0];
      xrc = xr_[H_];
      xhc = xr_[2 * H_];
    }
  }
  barrier_lds();

  for (int it = 0; it < T_; ++it) {
    const int t = dir ? (T_ - 1 - it) : it;

    // --- prefetch xp for step it+1 (hidden under the dot phase) ---
    XT xzn = xzc, xrn = xrc, xhn = xhc;
    if (gateT && (it + 1 < T_)) {
      const int tn = dir ? (t - 1) : (t + 1);
      const XT* xr_ = xbase + ((size_t)tn * B_ + b0 + grow) * G_ + gu;
      xzn = xr_[0];
      xrn = xr_[H_];
      xhn = xr_[2 * H_];
    }

    // --- dot phase: packed-fp32 FMA, 4 cols x 2 rows per thread ---
    f32x2 a00 = {0.f, 0.f}, a01 = {0.f, 0.f}, a02 = {0.f, 0.f}, a03 = {0.f, 0.f};
    f32x2 a10 = {0.f, 0.f}, a11 = {0.f, 0.f}, a12 = {0.f, 0.f}, a13 = {0.f, 0.f};
#define FMA2(acc, h4, u4)                                              \
  {                                                                    \
    const f32x2* hp_ = (const f32x2*)&(h4);                            \
    const f32x2* up_ = (const f32x2*)&(u4);                            \
    acc = __builtin_elementwise_fma(hp_[0], up_[0], acc);              \
    acc = __builtin_elementwise_fma(hp_[1], up_[1], acc);              \
  }
#define DOT_I(i, uA, uB, uC, uD)                                       \
  {                                                                    \
    float4 h0 = *(const float4*)&hbuf[0][(i) * 32 + kc4];              \
    float4 h1 = *(const float4*)&hbuf[1][(i) * 32 + kc4];              \
    FMA2(a00, h0, uA) FMA2(a01, h0, uB) FMA2(a02, h0, uC)              \
    FMA2(a03, h0, uD)                                                  \
    FMA2(a10, h1, uA) FMA2(a11, h1, uB) FMA2(a12, h1, uC)              \
    FMA2(a13, h1, uD)                                                  \
  }
    DOT_I(0, u00, u10, u20, u30)
    DOT_I(1, u01, u11, u21, u31)
    DOT_I(2, u02, u12, u22, u32)
    DOT_I(3, u03, u13, u23, u33)
#undef DOT_I
#undef FMA2

    float s00 = a00.x + a00.y, s01 = a01.x + a01.y;
    float s02 = a02.x + a02.y, s03 = a03.x + a03.y;
    float s10 = a10.x + a10.y, s11 = a11.x + a11.y;
    float s12 = a12.x + a12.y, s13 = a13.x + a13.y;
    s00 = dpp_red8(s00); s01 = dpp_red8(s01);
    s02 = dpp_red8(s02); s03 = dpp_red8(s03);
    s10 = dpp_red8(s10); s11 = dpp_red8(s11);
    s12 = dpp_red8(s12); s13 = dpp_red8(s13);

    const float va = wc == 0 ? s00 : wc == 1 ? s01 : wc == 2 ? s02 : s03;
    const float vb = wc == 0 ? s10 : wc == 1 ? s11 : wc == 2 ? s12 : s13;
    rec_s[wr][cg * 4 + wc] = (wr ? vb : va) + bmine;
    barrier_lds();

    // --- gate phase (first 256 threads) ---
    if (gateT) {
      const float xz = tof(xzc);
      const float xr = tof(xrc);
      const float xh = tof(xhc);
      const float rz = rec_s[grow][gu];
      const float rr = rec_s[grow][H_ + gu];
      const float rh = rec_s[grow][2 * H_ + gu];
      const float z = fsigmoid(xz + rz);
      const float r = fsigmoid(xr + rr);
      const float hh = ftanh(xh + r * rh);
      const float hold = hbuf[grow][gu];
      const float hn = z * hold + (1.f - z) * hh;
      hbuf[grow][gu] = hn;
      if constexpr (!LAST) {
        const size_t sidx =
            ((size_t)(b0 + grow) * T_ + t) * (2 * H_) + dir * H_ + gu;
        const unsigned short hi = f2bs(hn);
        seqH[sidx] = hi;
        seqL[sidx] = f2bs(hn - bs2f(hi));
      }
      xzc = xzn;
      xrc = xrn;
      xhc = xhn;
    }
    barrier_lds();
  }

  if constexpr (LAST) {
    if (gateT) fin[(size_t)(b0 + grow) * (2 * H_) + dir * H_ + gu] =
        hbuf[grow][gu];
  }
}

// ---------------------------------------------------------------------------
// Dense head: out[b] = sigmoid(fin[b][:] . Wd + bd)
// ---------------------------------------------------------------------------
__global__ void dense_kernel(const float* __restrict__ fin,
                             const float* __restrict__ Wd,
                             const float* __restrict__ bd,
                             float* __restrict__ out) {
  __shared__ float w[2 * H_];
  const int tid = threadIdx.x;
  w[tid] = Wd[tid];
  __syncthreads();
  float s = bd[0];
  const float* row = fin + tid * (2 * H_);
#pragma unroll 8
  for (int jj = 0; jj < 2 * H_; ++jj) s = fmaf(row[jj], w[jj], s);
  out[tid] = 1.f / (1.f + __expf(-s));
}

// ---------------------------------------------------------------------------
template <typename XT>
static void run_model(const float* x, const float* Ws, const float* Us,
                      const float* bs, const float* Wd, const float* bd,
                      float* out, char* ws, hipStream_t stream) {
  const size_t xpB = (size_t)2 * T_ * B_ * G_ * sizeof(XT);
  const size_t seqB = (size_t)B_ * T_ * 2 * H_ * 2;  // bf16 bits
  XT* xp = (XT*)ws;
  ushort* sHA = (ushort*)(ws + xpB);
  ushort* sLA = (ushort*)(ws + xpB + seqB);
  ushort* sHB = (ushort*)(ws + xpB + 2 * seqB);
  ushort* sLB = (ushort*)(ws + xpB + 3 * seqB);
  ushort* WhiT = (ushort*)(ws + xpB + 4 * seqB);
  ushort* WloT = WhiT + (size_t)768 * K_;
  float* fin = (float*)(ws + xpB + 4 * seqB + (size_t)2 * 768 * K_ * 2);

  convX_kernel<<<4096, 256, 0, stream>>>(x, sHB, sLB);

  const ushort* AHs[3] = {sHB, sHA, sHB};
  const ushort* ALs[3] = {sLB, sLA, sLB};
  ushort* oH[3] = {sHA, sHB, nullptr};
  ushort* oL[3] = {sLA, sLB, nullptr};

  for (int l = 0; l < 3; ++l) {
    const float* Wl = Ws + (size_t)l * 2 * K_ * G_;
    const float* bl = bs + (size_t)l * 4 * G_;
    const float* Ul = Us + (size_t)l * 2 * H_ * G_;
    convW_kernel<<<768, 256, 0, stream>>>(Wl, WhiT, WloT);
    gemm3_kernel<XT><<<dim3(M_ / 128, 6), 256, 0, stream>>>(
        AHs[l], ALs[l], WhiT, WloT, bl, xp);
    if (l < 2)
      rec_kernel<XT, false><<<dim3(B_ / 2, 2), 768, 0, stream>>>(
          xp, Ul, bl, oH[l], oL[l], nullptr);
    else
      rec_kernel<XT, true><<<dim3(B_ / 2, 2), 768, 0, stream>>>(
          xp, Ul, bl, nullptr, nullptr, fin);
  }
  dense_kernel<<<1, B_, 0, stream>>>(fin, Wd, bd, out);
}

extern "C" void kernel_launch(void* const* d_in, const int* in_sizes, int n_in,
                              void* d_out, int out_size, void* d_ws,
                              size_t ws_size, hipStream_t stream) {
  const float* x = (const float*)d_in[0];
  const float* Ws = (const float*)d_in[1];
  const float* Us = (const float*)d_in[2];
  const float* bs = (const float*)d_in[3];
  const float* Wd = (const float*)d_in[4];
  const float* bd = (const float*)d_in[5];
  float* out = (float*)d_out;
  char* ws = (char*)d_ws;

  const size_t seqB = (size_t)B_ * T_ * 2 * H_ * 2;
  const size_t wtB = (size_t)2 * 768 * K_ * 2;
  const size_t finB = (size_t)B_ * 2 * H_ * 4;
  const size_t xp32 = (size_t)2 * T_ * B_ * G_ * 4;
  const size_t tierA = xp32 + 4 * seqB + wtB + finB;      // ~641 MiB, fp32 xp
  if (ws_size >= tierA)
    run_model<float>(x, Ws, Us, bs, Wd, bd, out, ws, stream);
  else
    run_model<bf16>(x, Ws, Us, bs, Wd, bd, out, ws, stream);
}

// Round 10
// 2140.081 us; speedup vs baseline: 2.4502x; 1.0641x over previous
//
#include <hip/hip_runtime.h>
#include <hip/hip_bf16.h>

#define DEV __device__ __forceinline__

constexpr int B_ = 256;   // batch
constexpr int T_ = 512;   // time
constexpr int H_ = 128;   // GRU units
constexpr int K_ = 256;   // input dim per layer (D = 2H = 256 for all layers)
constexpr int G_ = 384;   // 3H
constexpr int M_ = B_ * T_;
constexpr int LDSROW = 72;  // ushorts per LDS tile row (64 data + 8 pad)

using bf16 = __hip_bfloat16;
typedef short bf16x8 __attribute__((ext_vector_type(8)));
typedef float f32x4 __attribute__((ext_vector_type(4)));
typedef float f32x2 __attribute__((ext_vector_type(2)));

DEV float tof(float x) { return x; }
DEV float tof(bf16 x) { return __bfloat162float(x); }
DEV void stor(float* p, float v) { *p = v; }
DEV void stor(bf16* p, float v) { *p = __float2bfloat16(v); }

// float -> bf16 bits, round-to-nearest-even
DEV unsigned short f2bs(float f) {
  union { float f; unsigned u; } v;
  v.f = f;
  unsigned r = (v.u + 0x7FFFu + ((v.u >> 16) & 1u)) >> 16;
  return (unsigned short)r;
}
DEV float bs2f(unsigned short s) {
  union { unsigned u; float f; } v;
  v.u = ((unsigned)s) << 16;
  return v.f;
}

// v7: fast-rcp gate math (measured −25us/launch vs IEEE div).
DEV float fsigmoid(float x) {
  return __builtin_amdgcn_rcpf(1.f + __expf(-x));
}
DEV float ftanh(float x) {
  x = fminf(20.f, fmaxf(-20.f, x));
  float e = __expf(-2.f * x);
  return (1.f - e) * __builtin_amdgcn_rcpf(1.f + e);
}

// Barrier draining only LDS traffic (lgkmcnt), not global loads/stores.
DEV void barrier_lds() {
  asm volatile("s_waitcnt lgkmcnt(0)\n\ts_barrier" ::: "memory");
}

// Pin a float4 into VGPRs (opaque to the optimizer).
DEV void pin4(float4& v) {
  asm volatile("" : "+v"(v.x), "+v"(v.y), "+v"(v.z), "+v"(v.w));
}

DEV f32x4 mfma16(bf16x8 a, bf16x8 b, f32x4 c) {
  return __builtin_amdgcn_mfma_f32_16x16x32_bf16(a, b, c, 0, 0, 0);
}

// Single-stage DPP exchanges within 8-lane groups (bound_ctrl, full masks).
DEV float dppx1(float x) {  // lane ^ 1 (quad_perm [1,0,3,2])
  return __int_as_float(
      __builtin_amdgcn_update_dpp(0, __float_as_int(x), 0xB1, 0xF, 0xF, true));
}
DEV float dppx2(float x) {  // lane ^ 2 (quad_perm [2,3,0,1])
  return __int_as_float(
      __builtin_amdgcn_update_dpp(0, __float_as_int(x), 0x4E, 0xF, 0xF, true));
}
DEV float dppx7(float x) {  // lane ^ 7 (row_half_mirror)
  return __int_as_float(
      __builtin_amdgcn_update_dpp(0, __float_as_int(x), 0x141, 0xF, 0xF, true));
}

// ---------------------------------------------------------------------------
// convX: split fp32 x[M,256] into bf16 hi/lo arrays (layer-0 GEMM input).
// ---------------------------------------------------------------------------
__global__ __launch_bounds__(256) void convX_kernel(
    const float* __restrict__ x, ushort* __restrict__ hiA,
    ushort* __restrict__ loA) {
  const int n4 = M_ * K_ / 4;
  for (int idx = blockIdx.x * blockDim.x + threadIdx.x; idx < n4;
       idx += gridDim.x * blockDim.x) {
    float4 v = ((const float4*)x)[idx];
    ushort4 h, l;
    h.x = f2bs(v.x); l.x = f2bs(v.x - bs2f(h.x));
    h.y = f2bs(v.y); l.y = f2bs(v.y - bs2f(h.y));
    h.z = f2bs(v.z); l.z = f2bs(v.z - bs2f(h.z));
    h.w = f2bs(v.w); l.w = f2bs(v.w - bs2f(h.w));
    ((ushort4*)hiA)[idx] = h;
    ((ushort4*)loA)[idx] = l;
  }
}

// ---------------------------------------------------------------------------
// convW: W[dir][256][384] fp32 -> W^T hi/lo bf16 [768 ncol][256 k].
// ---------------------------------------------------------------------------
__global__ __launch_bounds__(256) void convW_kernel(
    const float* __restrict__ W, ushort* __restrict__ WhiT,
    ushort* __restrict__ WloT) {
  const int ncol = blockIdx.x;           // 0..767
  const int dir = ncol / G_, j = ncol % G_;
  const int k = threadIdx.x;             // 0..255
  const float f = W[((size_t)dir * K_ + k) * G_ + j];
  const unsigned short hi = f2bs(f);
  WhiT[(size_t)ncol * K_ + k] = hi;
  WloT[(size_t)ncol * K_ + k] = f2bs(f - bs2f(hi));
}

// ---------------------------------------------------------------------------
// gemm3: C[M,768] = A[M,256] @ W^T' + bias, bf16 hi/lo 3-term split MFMA.
// ---------------------------------------------------------------------------
template <typename XT>
__global__ __launch_bounds__(256, 2) void gemm3_kernel(
    const ushort* __restrict__ Ahi, const ushort* __restrict__ Alo,
    const ushort* __restrict__ WhiT, const ushort* __restrict__ WloT,
    const float* __restrict__ bbias, XT* __restrict__ xp) {
  const int m0 = blockIdx.x * 128;
  const int n0 = blockIdx.y * 128;
  const int tid = threadIdx.x;
  const int w = tid >> 6, lane = tid & 63;
  const int wm = w >> 1, wn = w & 1;
  const int col = lane & 15, quad = lane >> 4;

  __shared__ __align__(16) ushort AH[128 * LDSROW];
  __shared__ __align__(16) ushort AL[128 * LDSROW];
  __shared__ __align__(16) ushort BH[128 * LDSROW];
  __shared__ __align__(16) ushort BL[128 * LDSROW];

  f32x4 acc[4][4];
#pragma unroll
  for (int i = 0; i < 4; ++i)
#pragma unroll
    for (int n = 0; n < 4; ++n) acc[i][n] = (f32x4){0.f, 0.f, 0.f, 0.f};

  const ushort* gsrc = (w == 0) ? Ahi : (w == 1) ? Alo : (w == 2) ? WhiT : WloT;
  ushort* lds = (w == 0) ? AH : (w == 1) ? AL : (w == 2) ? BH : BL;
  const int rbase = (w < 2) ? m0 : n0;

  for (int kb = 0; kb < K_; kb += 64) {
#pragma unroll
    for (int q = 0; q < 16; ++q) {
      const int slot = q * 64 + lane;
      const int r = slot >> 3, s = slot & 7;
      bf16x8 v = *(const bf16x8*)(gsrc + (size_t)(rbase + r) * K_ + kb + s * 8);
      *(bf16x8*)&lds[r * LDSROW + s * 8] = v;
    }
    __syncthreads();
#pragma unroll
    for (int z = 0; z < 2; ++z) {
      const int cc8 = (z * 4 + quad) * 8;
      bf16x8 ah[4], al[4], bh[4], bl[4];
#pragma unroll
      for (int i = 0; i < 4; ++i) {
        const int row = wm * 64 + i * 16 + col;
        ah[i] = *(const bf16x8*)&AH[row * LDSROW + cc8];
        al[i] = *(const bf16x8*)&AL[row * LDSROW + cc8];
      }
#pragma unroll
      for (int n = 0; n < 4; ++n) {
        const int row = wn * 64 + n * 16 + col;
        bh[n] = *(const bf16x8*)&BH[row * LDSROW + cc8];
        bl[n] = *(const bf16x8*)&BL[row * LDSROW + cc8];
      }
#pragma unroll
      for (int i = 0; i < 4; ++i)
#pragma unroll
        for (int n = 0; n < 4; ++n) {
          acc[i][n] = mfma16(ah[i], bh[n], acc[i][n]);
          acc[i][n] = mfma16(al[i], bh[n], acc[i][n]);
          acc[i][n] = mfma16(ah[i], bl[n], acc[i][n]);
        }
    }
    __syncthreads();
  }

  const int dir = (n0 >= G_) ? 1 : 0;
#pragma unroll
  for (int n = 0; n < 4; ++n) {
    const int ncol = n0 + wn * 64 + n * 16 + col;
    const int g = ncol - dir * G_;
    const float bv = bbias[dir * 2 * G_ + g];
#pragma unroll
    for (int i = 0; i < 4; ++i) {
      const int mb = m0 + wm * 64 + i * 16 + quad * 4;
#pragma unroll
      for (int r = 0; r < 4; ++r) {
        const int m = mb + r;
        const int bb = m >> 9;          // T_ = 512
        const int t = m & (T_ - 1);
        stor(xp + ((size_t)(dir * T_ + t) * B_ + bb) * G_ + g,
             acc[i][n][r] + bv);
      }
    }
  }
}

DEV float4 ldU4(const float* U, int col, int k0) {
  float4 v;
  v.x = U[(size_t)(k0 + 0) * G_ + col];
  v.y = U[(size_t)(k0 + 1) * G_ + col];
  v.z = U[(size_t)(k0 + 2) * G_ + col];
  v.w = U[(size_t)(k0 + 3) * G_ + col];
  return v;
}

// ---------------------------------------------------------------------------
// Recurrence, v8 = v7 structure (measured 565us, VGPR 68) with the 8-lane
// reduction rewritten as a reduce-scatter butterfly via PERMUTED OPERAND
// LAYOUT. v7 computed all 8 full sums per lane (8 x dpp_red8 = 48 ops) then
// discarded 7/8 via cndmask chains. v8 chooses the linear lane-permutation
//   g(kc) = (kc&1?4:0) ^ (kc&2?2:0) ^ (kc&4?7:0)    (invertible, GF(2)^3)
// built so the 3 scatter stages pair lanes by xor1/xor2/xor7 — all free DPP
// controls (0xB1 / 0x4E / 0x141). The permutation is absorbed at zero cost:
//  - U columns loaded pre-permuted:  col = cg*4 + (m ^ (g&3))   (global addr)
//  - h rows read swapped per lane:   hA = hbuf[g>>2]            (LDS base)
//  - FMA block instruction-identical to v7 (static acc indices)
// Bookkeeping invariant j(lane,p) = p ^ g(lane) holds across stages since
// g(l^1)=g(l)^4, g(l^2)=g(l)^2, g(l^7)=g(l)^1. After the tree lane kc holds
// the full sum for (col = cg*4+(g&3), row = g>>2) -> direct rec_s write, no
// selection. Reduction: 48+6 ops -> 14 ops (saves ~40 VALU/thread/step).
// ---------------------------------------------------------------------------
template <typename XT, bool LAST>
__global__ __attribute__((amdgpu_flat_work_group_size(768, 768),
                          amdgpu_waves_per_eu(3, 3))) void rec_kernel(
    const XT* __restrict__ xp, const float* __restrict__ Ubase,
    const float* __restrict__ bbase, ushort* __restrict__ seqH,
    ushort* __restrict__ seqL, float* __restrict__ fin) {
  const int dir = blockIdx.y;
  const float* U = Ubase + dir * (H_ * G_);
  const float* bh = bbase + dir * (2 * G_) + G_;
  const int b0 = blockIdx.x * 2;
  const int tid = threadIdx.x;
  const int kc = tid & 7;        // position within 8-lane DPP group
  const int cg = tid >> 3;       // column group 0..95
  const int kc4 = kc * 4;

  // Reduce-scatter permutation (see header comment).
  const int g = ((kc & 1) ? 4 : 0) ^ ((kc & 2) ? 2 : 0) ^ ((kc & 4) ? 7 : 0);
  const int glo = g & 3;   // column permute within the 4-col group
  const int gb2 = g >> 2;  // sequence-row swap for this lane

  __shared__ __align__(16) float hbuf[2][H_];
  __shared__ float rec_s[2][G_];

  // U fragments: u{m}{i} covers col cg*4 + (m ^ glo), k in [i*32+kc*4, +4)
#define LDU(m, i) ldU4(U, cg * 4 + ((m) ^ glo), (i) * 32 + kc4)
  float4 u00 = LDU(0, 0), u01 = LDU(0, 1), u02 = LDU(0, 2), u03 = LDU(0, 3);
  float4 u10 = LDU(1, 0), u11 = LDU(1, 1), u12 = LDU(1, 2), u13 = LDU(1, 3);
  float4 u20 = LDU(2, 0), u21 = LDU(2, 1), u22 = LDU(2, 2), u23 = LDU(2, 3);
  float4 u30 = LDU(3, 0), u31 = LDU(3, 1), u32 = LDU(3, 2), u33 = LDU(3, 3);
#undef LDU
  pin4(u00); pin4(u01); pin4(u02); pin4(u03);
  pin4(u10); pin4(u11); pin4(u12); pin4(u13);
  pin4(u20); pin4(u21); pin4(u22); pin4(u23);
  pin4(u30); pin4(u31); pin4(u32); pin4(u33);

  // This lane's final output after the tree: (col cg*4+glo, row gb2).
  const float bmine = bh[cg * 4 + glo];

  // Per-lane swapped h-row bases (zero-cost part of the permutation).
  const float* hA = hbuf[gb2];
  const float* hB = hbuf[gb2 ^ 1];

  const int grow = tid >> 7;        // gate-phase row (tid < 256)
  const int gu = tid & (H_ - 1);    // gate-phase unit
  const bool gateT = tid < 2 * H_;

  if (gateT) hbuf[grow][gu] = 0.f;

  const XT* xbase = xp + (size_t)(dir * T_) * B_ * G_;

  XT xzc{}, xrc{}, xhc{};
  {
    const int t0 = dir ? (T_ - 1) : 0;
    if (gateT) {
      const XT* xr_ = xbase + ((size_t)t0 * B_ + b0 + grow) * G_ + gu;
      xzc = xr_[0];
      xrc = xr_[H_];
      xhc = xr_[2 * H_];
    }
  }
  barrier_lds();

  for (int it = 0; it < T_; ++it) {
    const int t = dir ? (T_ - 1 - it) : it;

    // --- prefetch xp for step it+1 (hidden under the dot phase) ---
    XT xzn = xzc, xrn = xrc, xhn = xhc;
    if (gateT && (it + 1 < T_)) {
      const int tn = dir ? (t - 1) : (t + 1);
      const XT* xr_ = xbase + ((size_t)tn * B_ + b0 + grow) * G_ + gu;
      xzn = xr_[0];
      xrn = xr_[H_];
      xhn = xr_[2 * H_];
    }

    // --- dot phase: packed-fp32 FMA, instruction-identical to v7 ---
    f32x2 a00 = {0.f, 0.f}, a01 = {0.f, 0.f}, a02 = {0.f, 0.f}, a03 = {0.f, 0.f};
    f32x2 a10 = {0.f, 0.f}, a11 = {0.f, 0.f}, a12 = {0.f, 0.f}, a13 = {0.f, 0.f};
#define FMA2(acc, h4, u4)                                              \
  {                                                                    \
    const f32x2* hp_ = (const f32x2*)&(h4);                            \
    const f32x2* up_ = (const f32x2*)&(u4);                            \
    acc = __builtin_elementwise_fma(hp_[0], up_[0], acc);              \
    acc = __builtin_elementwise_fma(hp_[1], up_[1], acc);              \
  }
#define DOT_I(i, uA, uB, uC, uD)                                       \
  {                                                                    \
    float4 h0 = *(const float4*)&hA[(i) * 32 + kc4];                   \
    float4 h1 = *(const float4*)&hB[(i) * 32 + kc4];                   \
    FMA2(a00, h0, uA) FMA2(a01, h0, uB) FMA2(a02, h0, uC)              \
    FMA2(a03, h0, uD)                                                  \
    FMA2(a10, h1, uA) FMA2(a11, h1, uB) FMA2(a12, h1, uC)              \
    FMA2(a13, h1, uD)                                                  \
  }
    DOT_I(0, u00, u10, u20, u30)
    DOT_I(1, u01, u11, u21, u31)
    DOT_I(2, u02, u12, u22, u32)
    DOT_I(3, u03, u13, u23, u33)
#undef DOT_I
#undef FMA2

    // Horizontal adds: s[p], p&3 = U-col slot m, p>>2 = h-slot (0=hA,1=hB).
    const float s0 = a00.x + a00.y, s1 = a01.x + a01.y;
    const float s2 = a02.x + a02.y, s3 = a03.x + a03.y;
    const float s4 = a10.x + a10.y, s5 = a11.x + a11.y;
    const float s6 = a12.x + a12.y, s7 = a13.x + a13.y;

    // Reduce-scatter tree: 7 DPP + 7 adds (invariant j = p ^ g preserved).
    const float r0 = s0 + dppx1(s4);
    const float r1 = s1 + dppx1(s5);
    const float r2 = s2 + dppx1(s6);
    const float r3 = s3 + dppx1(s7);
    const float t0v = r0 + dppx2(r2);
    const float t1v = r1 + dppx2(r3);
    const float v = t0v + dppx7(t1v);

    rec_s[gb2][cg * 4 + glo] = v + bmine;
    barrier_lds();

    // --- gate phase (first 256 threads) ---
    if (gateT) {
      const float xz = tof(xzc);
      const float xr = tof(xrc);
      const float xh = tof(xhc);
      const float rz = rec_s[grow][gu];
      const float rr = rec_s[grow][H_ + gu];
      const float rh = rec_s[grow][2 * H_ + gu];
      const float z = fsigmoid(xz + rz);
      const float r = fsigmoid(xr + rr);
      const float hh = ftanh(xh + r * rh);
      const float hold = hbuf[grow][gu];
      const float hn = z * hold + (1.f - z) * hh;
      hbuf[grow][gu] = hn;
      if constexpr (!LAST) {
        const size_t sidx =
            ((size_t)(b0 + grow) * T_ + t) * (2 * H_) + dir * H_ + gu;
        const unsigned short hi = f2bs(hn);
        seqH[sidx] = hi;
        seqL[sidx] = f2bs(hn - bs2f(hi));
      }
      xzc = xzn;
      xrc = xrn;
      xhc = xhn;
    }
    barrier_lds();
  }

  if constexpr (LAST) {
    if (gateT) fin[(size_t)(b0 + grow) * (2 * H_) + dir * H_ + gu] =
        hbuf[grow][gu];
  }
}

// ---------------------------------------------------------------------------
// Dense head: out[b] = sigmoid(fin[b][:] . Wd + bd)
// ---------------------------------------------------------------------------
__global__ void dense_kernel(const float* __restrict__ fin,
                             const float* __restrict__ Wd,
                             const float* __restrict__ bd,
                             float* __restrict__ out) {
  __shared__ float w[2 * H_];
  const int tid = threadIdx.x;
  w[tid] = Wd[tid];
  __syncthreads();
  float s = bd[0];
  const float* row = fin + tid * (2 * H_);
#pragma unroll 8
  for (int jj = 0; jj < 2 * H_; ++jj) s = fmaf(row[jj], w[jj], s);
  out[tid] = 1.f / (1.f + __expf(-s));
}

// ---------------------------------------------------------------------------
template <typename XT>
static void run_model(const float* x, const float* Ws, const float* Us,
                      const float* bs, const float* Wd, const float* bd,
                      float* out, char* ws, hipStream_t stream) {
  const size_t xpB = (size_t)2 * T_ * B_ * G_ * sizeof(XT);
  const size_t seqB = (size_t)B_ * T_ * 2 * H_ * 2;  // bf16 bits
  XT* xp = (XT*)ws;
  ushort* sHA = (ushort*)(ws + xpB);
  ushort* sLA = (ushort*)(ws + xpB + seqB);
  ushort* sHB = (ushort*)(ws + xpB + 2 * seqB);
  ushort* sLB = (ushort*)(ws + xpB + 3 * seqB);
  ushort* WhiT = (ushort*)(ws + xpB + 4 * seqB);
  ushort* WloT = WhiT + (size_t)768 * K_;
  float* fin = (float*)(ws + xpB + 4 * seqB + (size_t)2 * 768 * K_ * 2);

  convX_kernel<<<4096, 256, 0, stream>>>(x, sHB, sLB);

  const ushort* AHs[3] = {sHB, sHA, sHB};
  const ushort* ALs[3] = {sLB, sLA, sLB};
  ushort* oH[3] = {sHA, sHB, nullptr};
  ushort* oL[3] = {sLA, sLB, nullptr};

  for (int l = 0; l < 3; ++l) {
    const float* Wl = Ws + (size_t)l * 2 * K_ * G_;
    const float* bl = bs + (size_t)l * 4 * G_;
    const float* Ul = Us + (size_t)l * 2 * H_ * G_;
    convW_kernel<<<768, 256, 0, stream>>>(Wl, WhiT, WloT);
    gemm3_kernel<XT><<<dim3(M_ / 128, 6), 256, 0, stream>>>(
        AHs[l], ALs[l], WhiT, WloT, bl, xp);
    if (l < 2)
      rec_kernel<XT, false><<<dim3(B_ / 2, 2), 768, 0, stream>>>(
          xp, Ul, bl, oH[l], oL[l], nullptr);
    else
      rec_kernel<XT, true><<<dim3(B_ / 2, 2), 768, 0, stream>>>(
          xp, Ul, bl, nullptr, nullptr, fin);
  }
  dense_kernel<<<1, B_, 0, stream>>>(fin, Wd, bd, out);
}

extern "C" void kernel_launch(void* const* d_in, const int* in_sizes, int n_in,
                              void* d_out, int out_size, void* d_ws,
                              size_t ws_size, hipStream_t stream) {
  const float* x = (const float*)d_in[0];
  const float* Ws = (const float*)d_in[1];
  const float* Us = (const float*)d_in[2];
  const float* bs = (const float*)d_in[3];
  const float* Wd = (const float*)d_in[4];
  const float* bd = (const float*)d_in[5];
  float* out = (float*)d_out;
  char* ws = (char*)d_ws;

  const size_t seqB = (size_t)B_ * T_ * 2 * H_ * 2;
  const size_t wtB = (size_t)2 * 768 * K_ * 2;
  const size_t finB = (size_t)B_ * 2 * H_ * 4;
  const size_t xp32 = (size_t)2 * T_ * B_ * G_ * 4;
  const size_t tierA = xp32 + 4 * seqB + wtB + finB;      // ~641 MiB, fp32 xp
  if (ws_size >= tierA)
    run_model<float>(x, Ws, Us, bs, Wd, bd, out, ws, stream);
  else
    run_model<bf16>(x, Ws, Us, bs, Wd, bd, out, ws, stream);
}